// Round 3
// baseline (315.773 us; speedup 1.0000x reference)
//
#include <hip/hip_runtime.h>
#include <hip/hip_bf16.h>

// CausalSelfAttention on gfx950 — round 9.
// r8: attn rewrite landed (attn < 95us, total 333->299). New #1 dispatch:
// gemm_qkv 96us, MfmaUtil 22%, HBM 9.5% — the 128^2 2-barrier-per-K-step
// structure's stage+drain overhead dominates (16 MFMA per barrier pair).
// This round: gemm_qkv -> 256x256 tile, BK=64, 512 thr (8 waves 2Mx4N),
// 128KiB LDS double-buffer, global_load_lds staging with XOR-chunk swizzle
// (0-conflict family), pipelined: stage kt+2 after the read-barrier,
// s_waitcnt vmcnt(8) (never 0 mid-loop), 2 barriers per 64-MFMA K-tile,
// setprio(1) around MFMA clusters. gemm_out keeps 128^2 (N=1024 grid too
// small for 256^2) but gets the same pipelined double-buffer. attn unchanged.

typedef unsigned short u16;
typedef __attribute__((ext_vector_type(8))) short short8;
typedef __attribute__((ext_vector_type(4))) float f32x4;

#define N_HEADS 16
#define HEAD_DIM 64
#define TSEQ 2048
#define BATCH 4
#define MROWS (BATCH * TSEQ)   // 8192
#define N3 3072                // 3*D_MODEL

__device__ __forceinline__ void cp16(const u16* g, u16* l) {
  __builtin_amdgcn_global_load_lds((const __attribute__((address_space(1))) void*)g,
                                   (__attribute__((address_space(3))) void*)l, 16, 0, 0);
}

__device__ __forceinline__ f32x4 mfma16(short8 a, short8 b, f32x4 c) {
  return __builtin_amdgcn_mfma_f32_16x16x32_bf16(a, b, c, 0, 0, 0);
}

__device__ __forceinline__ u16 f2b(float f) {
  __hip_bfloat16 h = __float2bfloat16(f);
  return *reinterpret_cast<u16*>(&h);
}

// ------------------------------------------------------------ fp32 -> bf16
__global__ __launch_bounds__(256) void cvt_f32_bf16(const float* __restrict__ src,
                                                    u16* __restrict__ dst, int n4) {
  int i = blockIdx.x * 256 + threadIdx.x;
  if (i < n4) {
    float4 v = *(const float4*)(src + (size_t)i * 4);
    u16* d = dst + (size_t)i * 4;
    d[0] = f2b(v.x); d[1] = f2b(v.y); d[2] = f2b(v.z); d[3] = f2b(v.w);
  }
}

// ------------------------------------------- fp32 [R][Cn] -> bf16 [Cn][R]
__global__ void transpose_cvt(const float* __restrict__ src, u16* __restrict__ dst,
                              int R, int Cn) {
  __shared__ float tile[32][33];
  int c0 = blockIdx.x * 32, r0 = blockIdx.y * 32;
  for (int i = threadIdx.y; i < 32; i += 8)
    tile[i][threadIdx.x] = src[(size_t)(r0 + i) * Cn + c0 + threadIdx.x];
  __syncthreads();
  for (int i = threadIdx.y; i < 32; i += 8)
    dst[(size_t)(c0 + i) * R + r0 + threadIdx.x] = f2b(tile[threadIdx.x][i]);
}

// -------------------------------------------------- 128^2 GEMM core (pipelined)
// Double-buffered LDS (Asm/Bsm = [2][4096] u16), stage kt+2 after the
// read-barrier, vmcnt(4) mid-loop (tile kt+1 stays in flight), 2 barriers
// per BK=32 K-step.
__device__ __forceinline__ void gemm128_core(const u16* __restrict__ A,
                                             const u16* __restrict__ Bt,
                                             int m0, int n0,
                                             u16* Asm, u16* Bsm,
                                             f32x4 acc[4][4]) {
  const int tid = threadIdx.x;
  const int w = tid >> 6;
  const int lane = tid & 63;
  const int quad = lane >> 4;
  const int l16 = lane & 15;
  const int wm = (w >> 1) * 64;
  const int wn = (w & 1) * 64;

#pragma unroll
  for (int i = 0; i < 4; ++i)
#pragma unroll
    for (int j = 0; j < 4; ++j) acc[i][j] = (f32x4){0.f, 0.f, 0.f, 0.f};

#define STG128(k0_, b_)                                                     \
  do {                                                                      \
    _Pragma("unroll")                                                       \
    for (int p = 0; p < 2; ++p) {                                           \
      int s = p * 256 + tid;                                                \
      int row = s >> 2;                                                     \
      int c4 = (s & 3) ^ ((row >> 1) & 3);                                  \
      cp16(A + (size_t)(m0 + row) * 1024 + (k0_) + c4 * 8,                  \
           Asm + (size_t)(b_) * 4096 + (p * 256 + w * 64) * 8);             \
      cp16(Bt + (size_t)(n0 + row) * 1024 + (k0_) + c4 * 8,                 \
           Bsm + (size_t)(b_) * 4096 + (p * 256 + w * 64) * 8);             \
    }                                                                       \
  } while (0)

  STG128(0, 0);
  STG128(32, 1);
  asm volatile("s_waitcnt vmcnt(4)" ::: "memory");  // tile 0 landed
  asm volatile("s_barrier" ::: "memory");

  for (int kt = 0; kt < 32; ++kt) {
    const u16* Ab = Asm + (kt & 1) * 4096;
    const u16* Bb = Bsm + (kt & 1) * 4096;
    short8 a[4], b[4];
#pragma unroll
    for (int i = 0; i < 4; ++i) {
      int row = wm + i * 16 + l16;
      int c4 = quad ^ ((row >> 1) & 3);
      a[i] = *(const short8*)(Ab + row * 32 + c4 * 8);
    }
#pragma unroll
    for (int j = 0; j < 4; ++j) {
      int row = wn + j * 16 + l16;
      int c4 = quad ^ ((row >> 1) & 3);
      b[j] = *(const short8*)(Bb + row * 32 + c4 * 8);
    }
    __builtin_amdgcn_s_setprio(1);
#pragma unroll
    for (int i = 0; i < 4; ++i)
#pragma unroll
      for (int j = 0; j < 4; ++j)
        acc[i][j] = mfma16(a[i], b[j], acc[i][j]);
    __builtin_amdgcn_s_setprio(0);

    asm volatile("s_barrier" ::: "memory");  // all waves done reading buf
    if (kt + 2 < 32) {
      STG128((kt + 2) * 32, kt & 1);         // into freed buf; stays in flight
      asm volatile("s_waitcnt vmcnt(4)" ::: "memory");  // tile kt+1 landed
    } else if (kt + 1 < 32) {
      asm volatile("s_waitcnt vmcnt(0)" ::: "memory");  // last tile: drain
    }
    asm volatile("s_barrier" ::: "memory");  // buf(kt+1) ready for all waves
  }
#undef STG128
}

// ------------------------------------------- QKV GEMM: 256^2 tile, 8 waves
// M=8192 N=3072 K=1024. Wave w: wr=w>>2 (0..1, 128 rows), wc=w&3 (0..3, 64
// cols). acc[8][4] per wave = 128 f32. LDS: A/B [2][256][64] bf16 = 128 KiB.
// Row = 128B = 32 banks; chunk c8 of 8x16B XOR'd by (row&7) — same 0-conflict
// family as the attn kernel. Pipeline: 2 tiles staged ahead, vmcnt(8) only.
__global__ __launch_bounds__(512, 2) void gemm_qkv_256(
    const u16* __restrict__ x, const u16* __restrict__ Wt,
    const float* __restrict__ bias,
    u16* __restrict__ qb, u16* __restrict__ kb, u16* __restrict__ vtb) {
  __shared__ __align__(16) u16 Asm[2][256 * 64];   // 64 KiB
  __shared__ __align__(16) u16 Bsm[2][256 * 64];   // 64 KiB
  const int tid = threadIdx.x;          // 0..511
  const int w = tid >> 6;               // 0..7
  const int lane = tid & 63;
  const int quad = lane >> 4, l16 = lane & 15;
  const int wr = w >> 2;                // 0..1
  const int wc = w & 3;                 // 0..3
  const int m0 = blockIdx.y * 256;
  const int n0 = blockIdx.x * 256;

  f32x4 acc[8][4];
#pragma unroll
  for (int mi = 0; mi < 8; ++mi)
#pragma unroll
    for (int nj = 0; nj < 4; ++nj) acc[mi][nj] = (f32x4){0.f, 0.f, 0.f, 0.f};

  // stage K-tile kt (BK=64) into buffer b: 8 cp16/thread (4 A + 4 B).
  // 256 rows x 8 chunks = 2048 chunks per operand; thread covers s = p*512+tid.
  // LDS position (s&7) holds global chunk (s&7)^(row&7)  [involution].
#define STAGEQ(kt_, b_)                                                     \
  do {                                                                      \
    const u16* ga_ = x + (size_t)m0 * 1024 + (kt_) * 64;                    \
    const u16* gb_ = Wt + (size_t)n0 * 1024 + (kt_) * 64;                   \
    _Pragma("unroll")                                                       \
    for (int p = 0; p < 4; ++p) {                                           \
      int s_ = p * 512 + tid;                                               \
      int row_ = s_ >> 3;               /* 0..255 */                        \
      int c8_ = (s_ & 7) ^ (row_ & 7);                                      \
      cp16(ga_ + (size_t)row_ * 1024 + c8_ * 8,                             \
           &Asm[b_][(p * 512 + w * 64) * 8]);                               \
      cp16(gb_ + (size_t)row_ * 1024 + c8_ * 8,                             \
           &Bsm[b_][(p * 512 + w * 64) * 8]);                               \
    }                                                                       \
  } while (0)

  STAGEQ(0, 0);
  STAGEQ(1, 1);
  asm volatile("s_waitcnt vmcnt(8)" ::: "memory");  // tile 0 landed
  asm volatile("s_barrier" ::: "memory");

  const int NT = 1024 / 64;  // 16
  for (int kt = 0; kt < NT; ++kt) {
    const u16* Ab = Asm[kt & 1];
    const u16* Bb = Bsm[kt & 1];
#pragma unroll
    for (int ks = 0; ks < 2; ++ks) {
      short8 a[8], b[4];
#pragma unroll
      for (int mi = 0; mi < 8; ++mi) {
        int row = wr * 128 + mi * 16 + l16;
        int c = (ks * 4 + quad) ^ (row & 7);
        a[mi] = *(const short8*)(Ab + row * 64 + c * 8);
      }
#pragma unroll
      for (int nj = 0; nj < 4; ++nj) {
        int row = wc * 64 + nj * 16 + l16;
        int c = (ks * 4 + quad) ^ (row & 7);
        b[nj] = *(const short8*)(Bb + row * 64 + c * 8);
      }
      __builtin_amdgcn_s_setprio(1);
#pragma unroll
      for (int mi = 0; mi < 8; ++mi)
#pragma unroll
        for (int nj = 0; nj < 4; ++nj)
          acc[mi][nj] = mfma16(a[mi], b[nj], acc[mi][nj]);
      __builtin_amdgcn_s_setprio(0);
    }

    asm volatile("s_barrier" ::: "memory");  // all waves done reading buf
    if (kt + 2 < NT) {
      STAGEQ(kt + 2, kt & 1);                // into freed buf; stays in flight
      asm volatile("s_waitcnt vmcnt(8)" ::: "memory");  // tile kt+1 landed
    } else if (kt + 1 < NT) {
      asm volatile("s_waitcnt vmcnt(0)" ::: "memory");  // last tile: drain
    }
    asm volatile("s_barrier" ::: "memory");  // buf(kt+1) ready for all waves
  }
#undef STAGEQ

  // epilogue: bias + scatter to q/k/v^T. `which` is block-uniform (256 | 1024).
#pragma unroll
  for (int nj = 0; nj < 4; ++nj) {
    int col = n0 + wc * 64 + nj * 16 + l16;
    float bv = bias[col];
    int which = col >> 10;     // 0=q 1=k 2=v
    int rem = col & 1023;
    int h = rem >> 6, d = rem & 63;
#pragma unroll
    for (int mi = 0; mi < 8; ++mi) {
#pragma unroll
      for (int r = 0; r < 4; ++r) {
        int m = m0 + wr * 128 + mi * 16 + quad * 4 + r;
        int b_ = m >> 11, t = m & 2047;
        int bh = b_ * N_HEADS + h;
        u16 o = f2b(acc[mi][nj][r] + bv);
        if (which == 0)
          qb[((size_t)(bh * TSEQ + t) << 6) + d] = o;
        else if (which == 1)
          kb[((size_t)(bh * TSEQ + t) << 6) + d] = o;
        else
          vtb[((size_t)((bh << 6) + d)) * TSEQ + t] = o;
      }
    }
  }
}

// ---------------------------------------------------------------- attention
// One block per (128-row q-tile, bh). 4 waves; wave w, m-frag mi covers q rows
// qt*128 + mi*64 + w*16 .. +15 (indexed by l16). K-tile = 64 keys, LDS
// double-buffer, raw barriers + fine-grained vmcnt (never 0 mid-loop).
// Swapped QK^T: s = mfma(Kfrag, Qfrag) -> lane (quad,l16) holds
// S[q=l16][key kappa(j*16+quad*4+r)] where the K staging placed key
// kappa(rho) = {rho5, rho3, rho2, rho4, rho1, rho0} at LDS row rho, i.e.
// lane quad holds exactly keys {quad*8+e} u {32+quad*8+e} — the PV A-operand
// k-slots. P never leaves the lane; no Psm, no lgkm drain.
__global__ __launch_bounds__(256, 5) void attn_kernel(const u16* __restrict__ qb,
                                                      const u16* __restrict__ kb,
                                                      const u16* __restrict__ vtb,
                                                      u16* __restrict__ ob) {
  const int qt = (TSEQ / 128 - 1) - blockIdx.x;  // 15..0 — heavy blocks first
  const int bh = blockIdx.y;                     // 0..63
  __shared__ __align__(16) u16 Ksm[2][4096];     // [buf][rho 64][d 64] swizzled
  __shared__ __align__(16) u16 Vsm[2][4096];     // [buf][d 64][t_k 64] swizzled
  const int tid = threadIdx.x;
  const int w = tid >> 6, lane = tid & 63, quad = lane >> 4, l16 = lane & 15;
  const int qbase = qt * 128;

  // Q fragments (B-operand layout == A-layout for 16x16x32), in registers
  short8 qf[2][2];
#pragma unroll
  for (int mi = 0; mi < 2; ++mi) {
    const u16* qr = qb + ((size_t)(bh * TSEQ + qbase + mi * 64 + w * 16 + l16)) * 64;
    qf[mi][0] = *(const short8*)(qr + quad * 8);
    qf[mi][1] = *(const short8*)(qr + 32 + quad * 8);
  }

  f32x4 o[2][4];
  float lp[2] = {0.f, 0.f};
#pragma unroll
  for (int mi = 0; mi < 2; ++mi)
#pragma unroll
    for (int j = 0; j < 4; ++j) o[mi][j] = (f32x4){0.f, 0.f, 0.f, 0.f};
  const float cexp = 0.18033688011112042f;  // (1/sqrt(64)) * log2(e)
  const float M = 10.0f;                    // static softmax shift

  const u16* kb_bh = kb + (size_t)bh * TSEQ * 64;
  const u16* vt_bh = vtb + (size_t)bh * 64 * TSEQ;
  const int nk = 2 * qt + 2;

  // stage k-tile kt into buffer b: 4 DMA issues per thread (vmcnt +=4).
  // K rows bit-permuted: LDS row rho <- key kappa(rho); V rows natural (d).
#define STAGE(kt_, b_)                                                        \
  do {                                                                        \
    const u16* kbase_ = kb_bh + (size_t)((kt_) * 64) * 64;                    \
    const u16* vbase_ = vt_bh + (kt_) * 64;                                   \
    _Pragma("unroll")                                                         \
    for (int p = 0; p < 2; ++p) {                                             \
      int s_ = p * 256 + tid;                                                 \
      int row_ = s_ >> 3;                                                     \
      int c8_ = (s_ & 7) ^ (row_ & 7);                                        \
      int krow_ = (row_ & 0x23) | ((row_ & 0x0C) << 1) | ((row_ & 0x10) >> 2);\
      cp16(kbase_ + krow_ * 64 + c8_ * 8, &Ksm[b_][(p * 256 + w * 64) * 8]);  \
      cp16(vbase_ + (size_t)row_ * TSEQ + c8_ * 8,                            \
           &Vsm[b_][(p * 256 + w * 64) * 8]);                                 \
    }                                                                         \
  } while (0)

  STAGE(0, 0);

  for (int kt = 0; kt < nk; ++kt) {
    // barrier 1: all waves finished READING buf((kt+1)&1) in iter kt-1
    asm volatile("s_barrier" ::: "memory");
    if (kt + 1 < nk) {
      STAGE(kt + 1, (kt + 1) & 1);               // DMA for kt+1 (stays in flight)
      asm volatile("s_waitcnt vmcnt(4)" ::: "memory");  // tile kt landed
    } else {
      asm volatile("s_waitcnt vmcnt(0)" ::: "memory");  // last tile: drain
    }
    // barrier 2: all waves' tile-kt DMA landed
    asm volatile("s_barrier" ::: "memory");

    const u16* Kb = Ksm[kt & 1];
    const u16* Vb = Vsm[kt & 1];

#pragma unroll
    for (int mi = 0; mi < 2; ++mi) {
      const int qmin = qbase + mi * 64 + w * 16;
      if (kt * 64 > qmin + 15) continue;   // whole fragment masked
      const int qlane = qmin + l16;

      // S^T = K Q^T : lane (quad,l16) gets S[q=l16][kappa(j*16+quad*4+r)]
      f32x4 s[4];
#pragma unroll
      for (int j = 0; j < 4; ++j) {
        int row = j * 16 + l16;
        int ca = quad ^ (row & 7);
        int cb = (4 + quad) ^ (row & 7);
        short8 k0 = *(const short8*)(Kb + row * 64 + ca * 8);
        short8 k1 = *(const short8*)(Kb + row * 64 + cb * 8);
        f32x4 z = (f32x4){0.f, 0.f, 0.f, 0.f};
        z = mfma16(k0, qf[mi][0], z);
        z = mfma16(k1, qf[mi][1], z);
        s[j] = z;
      }
      if (kt * 64 + 63 > qmin) {  // diagonal overlap: elementwise causal mask
#pragma unroll
        for (int j = 0; j < 4; ++j) {
#pragma unroll
          for (int r = 0; r < 4; ++r) {
            int kabs = kt * 64 + ((j >> 1) << 5) + (quad << 3) + ((j & 1) << 2) + r;
            if (kabs > qlane) s[j][r] = -1e30f;
          }
        }
      }
      // static-max softmax: p = exp2(s*cexp - M); pack straight into the
      // PV A-operand fragments (keys already lane-local in k-slot order).
      short8 ap0, ap1;
#pragma unroll
      for (int j = 0; j < 4; ++j) {
#pragma unroll
        for (int r = 0; r < 4; ++r) {
          float p_ = __builtin_amdgcn_exp2f(__builtin_fmaf(s[j][r], cexp, -M));
          lp[mi] += p_;
          u16 pb = f2b(p_);
          if (j < 2) ap0[j * 4 + r] = (short)pb;
          else       ap1[(j - 2) * 4 + r] = (short)pb;
        }
      }
      // O += P V : A = P (rows q=l16, k = quad*8+e), B = V^T (cols d=l16)
#pragma unroll
      for (int j = 0; j < 4; ++j) {
        int row = j * 16 + l16;  // d
        int ca = quad ^ (row & 7);
        int cb = (4 + quad) ^ (row & 7);
        short8 v0 = *(const short8*)(Vb + row * 64 + ca * 8);
        short8 v1 = *(const short8*)(Vb + row * 64 + cb * 8);
        o[mi][j] = mfma16(ap0, v0, o[mi][j]);
        o[mi][j] = mfma16(ap1, v1, o[mi][j]);
      }
    }
  }
#undef STAGE

  // epilogue: full softmax denominator = sum of lp across the 4 quads
  // (lane (quad,l16) holds the partial for q=l16 over keys quad*8+e, +32).
#pragma unroll
  for (int mi = 0; mi < 2; ++mi) {
    lp[mi] += __shfl_xor(lp[mi], 16);
    lp[mi] += __shfl_xor(lp[mi], 32);
  }
  const int b_ = bh >> 4, h = bh & 15;
#pragma unroll
  for (int mi = 0; mi < 2; ++mi) {
    float dn[4];
#pragma unroll
    for (int r = 0; r < 4; ++r)
      dn[r] = __shfl(lp[mi], (lane & 48) + quad * 4 + r);  // denom for q-row quad*4+r
#pragma unroll
    for (int j = 0; j < 4; ++j)
#pragma unroll
      for (int r = 0; r < 4; ++r) {
        int t = qbase + mi * 64 + w * 16 + quad * 4 + r;
        int d = j * 16 + l16;
        ob[((size_t)(b_ * TSEQ + t)) * 1024 + h * 64 + d] =
            f2b(o[mi][j][r] / dn[r]);
      }
  }
}

// ------------------------------------------------------- out GEMM (fp32 out)
__global__ __launch_bounds__(256) void gemm_out_kernel(
    const u16* __restrict__ attn, const u16* __restrict__ Wt,
    const float* __restrict__ bias, float* __restrict__ out) {
  __shared__ __align__(16) u16 Asm[2 * 4096];
  __shared__ __align__(16) u16 Bsm[2 * 4096];
  f32x4 acc[4][4];
  const int m0 = blockIdx.y * 128;
  const int n0 = blockIdx.x * 128;
  gemm128_core(attn, Wt, m0, n0, Asm, Bsm, acc);

  const int tid = threadIdx.x;
  const int w = tid >> 6, lane = tid & 63, quad = lane >> 4, l16 = lane & 15;
  const int wm = (w >> 1) * 64, wn = (w & 1) * 64;
#pragma unroll
  for (int j = 0; j < 4; ++j) {
    int col = n0 + wn + j * 16 + l16;
    float bv = bias[col];
#pragma unroll
    for (int i = 0; i < 4; ++i)
#pragma unroll
      for (int r = 0; r < 4; ++r) {
        int m = m0 + wm + i * 16 + quad * 4 + r;
        out[(size_t)m * 1024 + col] = acc[i][j][r] + bv;
      }
  }
}

// ---------------------------------------------------------------- launcher
extern "C" void kernel_launch(void* const* d_in, const int* in_sizes, int n_in,
                              void* d_out, int out_size, void* d_ws, size_t ws_size,
                              hipStream_t stream) {
  const float* x    = (const float*)d_in[0];   // [8192][1024] fp32
  const float* Wqkv = (const float*)d_in[1];   // [1024][3072] fp32
  const float* bqkv = (const float*)d_in[2];   // [3072] fp32
  const float* Wout = (const float*)d_in[3];   // [1024][1024] fp32
  const float* bout = (const float*)d_in[4];   // [1024] fp32
  float* out = (float*)d_out;                  // [8192][1024] fp32

  u16* ws = (u16*)d_ws;
  u16* xb     = ws;                                  // 8M   bf16 x
  u16* wqkv_t = xb + (size_t)MROWS * 1024;           // 3M   [3072][1024]
  u16* wout_t = wqkv_t + (size_t)N3 * 1024;          // 1M   [1024][1024]
  u16* qbuf   = wout_t + (size_t)1024 * 1024;        // 8M   [bh][t][d]
  u16* kbuf   = qbuf + (size_t)MROWS * 1024;         // 8M   [bh][t][d]
  u16* vtbuf  = kbuf + (size_t)MROWS * 1024;         // 8M   [bh][d][t]
  u16* obuf   = vtbuf + (size_t)MROWS * 1024;        // 8M   [b][t][c]
  (void)ws_size; (void)n_in; (void)in_sizes; (void)out_size;

  int n4 = MROWS * 1024 / 4;
  cvt_f32_bf16<<<(n4 + 255) / 256, 256, 0, stream>>>(x, xb, n4);
  transpose_cvt<<<dim3(N3 / 32, 1024 / 32), dim3(32, 8), 0, stream>>>(Wqkv, wqkv_t, 1024, N3);
  transpose_cvt<<<dim3(1024 / 32, 1024 / 32), dim3(32, 8), 0, stream>>>(Wout, wout_t, 1024, 1024);
  gemm_qkv_256<<<dim3(N3 / 256, MROWS / 256), 512, 0, stream>>>(xb, wqkv_t, bqkv, qbuf, kbuf, vtbuf);
  attn_kernel<<<dim3(TSEQ / 128, BATCH * N_HEADS), 256, 0, stream>>>(qbuf, kbuf, vtbuf, obuf);
  gemm_out_kernel<<<dim3(1024 / 128, MROWS / 128), 256, 0, stream>>>(obuf, wout_t, bout, out);
}

// Round 4
// 294.856 us; speedup vs baseline: 1.0709x; 1.0709x over previous
//
#include <hip/hip_runtime.h>
#include <hip/hip_bf16.h>

// CausalSelfAttention on gfx950 — round 10.
// r9 post-mortem: 256^2 2-phase qkv REGRESSED (96->151us): 128KiB LDS ->
// 1 block/CU -> 2 waves/SIMD, nothing hides the per-K-tile vmcnt+barrier;
// grid 384/256 CUs = 1.5 (quantization). Meanwhile gemm_out got ~38us
// FASTER from the pipelined double-buffer gemm128_core — that core wins.
// r10: gemm_qkv back to 128^2 tile ON the pipelined core (LDS 32KiB,
// multi-block/CU, 1536 blocks). gemm_out + attn unchanged from r9.

typedef unsigned short u16;
typedef __attribute__((ext_vector_type(8))) short short8;
typedef __attribute__((ext_vector_type(4))) float f32x4;

#define N_HEADS 16
#define HEAD_DIM 64
#define TSEQ 2048
#define BATCH 4
#define MROWS (BATCH * TSEQ)   // 8192
#define N3 3072                // 3*D_MODEL

__device__ __forceinline__ void cp16(const u16* g, u16* l) {
  __builtin_amdgcn_global_load_lds((const __attribute__((address_space(1))) void*)g,
                                   (__attribute__((address_space(3))) void*)l, 16, 0, 0);
}

__device__ __forceinline__ f32x4 mfma16(short8 a, short8 b, f32x4 c) {
  return __builtin_amdgcn_mfma_f32_16x16x32_bf16(a, b, c, 0, 0, 0);
}

__device__ __forceinline__ u16 f2b(float f) {
  __hip_bfloat16 h = __float2bfloat16(f);
  return *reinterpret_cast<u16*>(&h);
}

// ------------------------------------------------------------ fp32 -> bf16
__global__ __launch_bounds__(256) void cvt_f32_bf16(const float* __restrict__ src,
                                                    u16* __restrict__ dst, int n4) {
  int i = blockIdx.x * 256 + threadIdx.x;
  if (i < n4) {
    float4 v = *(const float4*)(src + (size_t)i * 4);
    u16* d = dst + (size_t)i * 4;
    d[0] = f2b(v.x); d[1] = f2b(v.y); d[2] = f2b(v.z); d[3] = f2b(v.w);
  }
}

// ------------------------------------------- fp32 [R][Cn] -> bf16 [Cn][R]
__global__ void transpose_cvt(const float* __restrict__ src, u16* __restrict__ dst,
                              int R, int Cn) {
  __shared__ float tile[32][33];
  int c0 = blockIdx.x * 32, r0 = blockIdx.y * 32;
  for (int i = threadIdx.y; i < 32; i += 8)
    tile[i][threadIdx.x] = src[(size_t)(r0 + i) * Cn + c0 + threadIdx.x];
  __syncthreads();
  for (int i = threadIdx.y; i < 32; i += 8)
    dst[(size_t)(c0 + i) * R + r0 + threadIdx.x] = f2b(tile[threadIdx.x][i]);
}

// -------------------------------------------------- 128^2 GEMM core (pipelined)
// Double-buffered LDS (Asm/Bsm = [2][4096] u16), stage kt+2 after the
// read-barrier, vmcnt(4) mid-loop (tile kt+1 stays in flight), 2 barriers
// per BK=32 K-step. Proven correct+faster via gemm_out in r9.
__device__ __forceinline__ void gemm128_core(const u16* __restrict__ A,
                                             const u16* __restrict__ Bt,
                                             int m0, int n0,
                                             u16* Asm, u16* Bsm,
                                             f32x4 acc[4][4]) {
  const int tid = threadIdx.x;
  const int w = tid >> 6;
  const int lane = tid & 63;
  const int quad = lane >> 4;
  const int l16 = lane & 15;
  const int wm = (w >> 1) * 64;
  const int wn = (w & 1) * 64;

#pragma unroll
  for (int i = 0; i < 4; ++i)
#pragma unroll
    for (int j = 0; j < 4; ++j) acc[i][j] = (f32x4){0.f, 0.f, 0.f, 0.f};

#define STG128(k0_, b_)                                                     \
  do {                                                                      \
    _Pragma("unroll")                                                       \
    for (int p = 0; p < 2; ++p) {                                           \
      int s = p * 256 + tid;                                                \
      int row = s >> 2;                                                     \
      int c4 = (s & 3) ^ ((row >> 1) & 3);                                  \
      cp16(A + (size_t)(m0 + row) * 1024 + (k0_) + c4 * 8,                  \
           Asm + (size_t)(b_) * 4096 + (p * 256 + w * 64) * 8);             \
      cp16(Bt + (size_t)(n0 + row) * 1024 + (k0_) + c4 * 8,                 \
           Bsm + (size_t)(b_) * 4096 + (p * 256 + w * 64) * 8);             \
    }                                                                       \
  } while (0)

  STG128(0, 0);
  STG128(32, 1);
  asm volatile("s_waitcnt vmcnt(4)" ::: "memory");  // tile 0 landed
  asm volatile("s_barrier" ::: "memory");

  for (int kt = 0; kt < 32; ++kt) {
    const u16* Ab = Asm + (kt & 1) * 4096;
    const u16* Bb = Bsm + (kt & 1) * 4096;
    short8 a[4], b[4];
#pragma unroll
    for (int i = 0; i < 4; ++i) {
      int row = wm + i * 16 + l16;
      int c4 = quad ^ ((row >> 1) & 3);
      a[i] = *(const short8*)(Ab + row * 32 + c4 * 8);
    }
#pragma unroll
    for (int j = 0; j < 4; ++j) {
      int row = wn + j * 16 + l16;
      int c4 = quad ^ ((row >> 1) & 3);
      b[j] = *(const short8*)(Bb + row * 32 + c4 * 8);
    }
    __builtin_amdgcn_s_setprio(1);
#pragma unroll
    for (int i = 0; i < 4; ++i)
#pragma unroll
      for (int j = 0; j < 4; ++j)
        acc[i][j] = mfma16(a[i], b[j], acc[i][j]);
    __builtin_amdgcn_s_setprio(0);

    asm volatile("s_barrier" ::: "memory");  // all waves done reading buf
    if (kt + 2 < 32) {
      STG128((kt + 2) * 32, kt & 1);         // into freed buf; stays in flight
      asm volatile("s_waitcnt vmcnt(4)" ::: "memory");  // tile kt+1 landed
    } else if (kt + 1 < 32) {
      asm volatile("s_waitcnt vmcnt(0)" ::: "memory");  // last tile: drain
    }
    asm volatile("s_barrier" ::: "memory");  // buf(kt+1) ready for all waves
  }
#undef STG128
}

// ---------------------------------------------------------------- QKV GEMM
__global__ __launch_bounds__(256) void gemm_qkv_kernel(
    const u16* __restrict__ x, const u16* __restrict__ Wt,
    const float* __restrict__ bias,
    u16* __restrict__ qb, u16* __restrict__ kb, u16* __restrict__ vtb) {
  __shared__ __align__(16) u16 Asm[2 * 4096];
  __shared__ __align__(16) u16 Bsm[2 * 4096];
  f32x4 acc[4][4];
  const int m0 = blockIdx.y * 128;
  const int n0 = blockIdx.x * 128;
  gemm128_core(x, Wt, m0, n0, Asm, Bsm, acc);

  const int tid = threadIdx.x;
  const int w = tid >> 6, lane = tid & 63, quad = lane >> 4, l16 = lane & 15;
  const int wm = (w >> 1) * 64, wn = (w & 1) * 64;
#pragma unroll
  for (int j = 0; j < 4; ++j) {
    int col = n0 + wn + j * 16 + l16;
    float bv = bias[col];
    int which = col >> 10;     // 0=q 1=k 2=v
    int rem = col & 1023;
    int h = rem >> 6, d = rem & 63;
#pragma unroll
    for (int i = 0; i < 4; ++i) {
#pragma unroll
      for (int r = 0; r < 4; ++r) {
        int m = m0 + wm + i * 16 + quad * 4 + r;
        int b_ = m >> 11, t = m & 2047;
        int bh = b_ * N_HEADS + h;
        u16 o = f2b(acc[i][j][r] + bv);
        if (which == 0)
          qb[((size_t)(bh * TSEQ + t) << 6) + d] = o;
        else if (which == 1)
          kb[((size_t)(bh * TSEQ + t) << 6) + d] = o;
        else
          vtb[((size_t)((bh << 6) + d)) * TSEQ + t] = o;
      }
    }
  }
}

// ---------------------------------------------------------------- attention
// One block per (128-row q-tile, bh). 4 waves; wave w, m-frag mi covers q rows
// qt*128 + mi*64 + w*16 .. +15 (indexed by l16). K-tile = 64 keys, LDS
// double-buffer, raw barriers + fine-grained vmcnt (never 0 mid-loop).
// Swapped QK^T: s = mfma(Kfrag, Qfrag) -> lane (quad,l16) holds
// S[q=l16][key kappa(j*16+quad*4+r)] where the K staging placed key
// kappa(rho) = {rho5, rho3, rho2, rho4, rho1, rho0} at LDS row rho, i.e.
// lane quad holds exactly keys {quad*8+e} u {32+quad*8+e} — the PV A-operand
// k-slots. P never leaves the lane; no Psm, no lgkm drain.
__global__ __launch_bounds__(256, 5) void attn_kernel(const u16* __restrict__ qb,
                                                      const u16* __restrict__ kb,
                                                      const u16* __restrict__ vtb,
                                                      u16* __restrict__ ob) {
  const int qt = (TSEQ / 128 - 1) - blockIdx.x;  // 15..0 — heavy blocks first
  const int bh = blockIdx.y;                     // 0..63
  __shared__ __align__(16) u16 Ksm[2][4096];     // [buf][rho 64][d 64] swizzled
  __shared__ __align__(16) u16 Vsm[2][4096];     // [buf][d 64][t_k 64] swizzled
  const int tid = threadIdx.x;
  const int w = tid >> 6, lane = tid & 63, quad = lane >> 4, l16 = lane & 15;
  const int qbase = qt * 128;

  // Q fragments (B-operand layout == A-layout for 16x16x32), in registers
  short8 qf[2][2];
#pragma unroll
  for (int mi = 0; mi < 2; ++mi) {
    const u16* qr = qb + ((size_t)(bh * TSEQ + qbase + mi * 64 + w * 16 + l16)) * 64;
    qf[mi][0] = *(const short8*)(qr + quad * 8);
    qf[mi][1] = *(const short8*)(qr + 32 + quad * 8);
  }

  f32x4 o[2][4];
  float lp[2] = {0.f, 0.f};
#pragma unroll
  for (int mi = 0; mi < 2; ++mi)
#pragma unroll
    for (int j = 0; j < 4; ++j) o[mi][j] = (f32x4){0.f, 0.f, 0.f, 0.f};
  const float cexp = 0.18033688011112042f;  // (1/sqrt(64)) * log2(e)
  const float M = 10.0f;                    // static softmax shift

  const u16* kb_bh = kb + (size_t)bh * TSEQ * 64;
  const u16* vt_bh = vtb + (size_t)bh * 64 * TSEQ;
  const int nk = 2 * qt + 2;

  // stage k-tile kt into buffer b: 4 DMA issues per thread (vmcnt +=4).
  // K rows bit-permuted: LDS row rho <- key kappa(rho); V rows natural (d).
#define STAGE(kt_, b_)                                                        \
  do {                                                                        \
    const u16* kbase_ = kb_bh + (size_t)((kt_) * 64) * 64;                    \
    const u16* vbase_ = vt_bh + (kt_) * 64;                                   \
    _Pragma("unroll")                                                         \
    for (int p = 0; p < 2; ++p) {                                             \
      int s_ = p * 256 + tid;                                                 \
      int row_ = s_ >> 3;                                                     \
      int c8_ = (s_ & 7) ^ (row_ & 7);                                        \
      int krow_ = (row_ & 0x23) | ((row_ & 0x0C) << 1) | ((row_ & 0x10) >> 2);\
      cp16(kbase_ + krow_ * 64 + c8_ * 8, &Ksm[b_][(p * 256 + w * 64) * 8]);  \
      cp16(vbase_ + (size_t)row_ * TSEQ + c8_ * 8,                            \
           &Vsm[b_][(p * 256 + w * 64) * 8]);                                 \
    }                                                                         \
  } while (0)

  STAGE(0, 0);

  for (int kt = 0; kt < nk; ++kt) {
    // barrier 1: all waves finished READING buf((kt+1)&1) in iter kt-1
    asm volatile("s_barrier" ::: "memory");
    if (kt + 1 < nk) {
      STAGE(kt + 1, (kt + 1) & 1);               // DMA for kt+1 (stays in flight)
      asm volatile("s_waitcnt vmcnt(4)" ::: "memory");  // tile kt landed
    } else {
      asm volatile("s_waitcnt vmcnt(0)" ::: "memory");  // last tile: drain
    }
    // barrier 2: all waves' tile-kt DMA landed
    asm volatile("s_barrier" ::: "memory");

    const u16* Kb = Ksm[kt & 1];
    const u16* Vb = Vsm[kt & 1];

#pragma unroll
    for (int mi = 0; mi < 2; ++mi) {
      const int qmin = qbase + mi * 64 + w * 16;
      if (kt * 64 > qmin + 15) continue;   // whole fragment masked
      const int qlane = qmin + l16;

      // S^T = K Q^T : lane (quad,l16) gets S[q=l16][kappa(j*16+quad*4+r)]
      f32x4 s[4];
#pragma unroll
      for (int j = 0; j < 4; ++j) {
        int row = j * 16 + l16;
        int ca = quad ^ (row & 7);
        int cb = (4 + quad) ^ (row & 7);
        short8 k0 = *(const short8*)(Kb + row * 64 + ca * 8);
        short8 k1 = *(const short8*)(Kb + row * 64 + cb * 8);
        f32x4 z = (f32x4){0.f, 0.f, 0.f, 0.f};
        z = mfma16(k0, qf[mi][0], z);
        z = mfma16(k1, qf[mi][1], z);
        s[j] = z;
      }
      if (kt * 64 + 63 > qmin) {  // diagonal overlap: elementwise causal mask
#pragma unroll
        for (int j = 0; j < 4; ++j) {
#pragma unroll
          for (int r = 0; r < 4; ++r) {
            int kabs = kt * 64 + ((j >> 1) << 5) + (quad << 3) + ((j & 1) << 2) + r;
            if (kabs > qlane) s[j][r] = -1e30f;
          }
        }
      }
      // static-max softmax: p = exp2(s*cexp - M); pack straight into the
      // PV A-operand fragments (keys already lane-local in k-slot order).
      short8 ap0, ap1;
#pragma unroll
      for (int j = 0; j < 4; ++j) {
#pragma unroll
        for (int r = 0; r < 4; ++r) {
          float p_ = __builtin_amdgcn_exp2f(__builtin_fmaf(s[j][r], cexp, -M));
          lp[mi] += p_;
          u16 pb = f2b(p_);
          if (j < 2) ap0[j * 4 + r] = (short)pb;
          else       ap1[(j - 2) * 4 + r] = (short)pb;
        }
      }
      // O += P V : A = P (rows q=l16, k = quad*8+e), B = V^T (cols d=l16)
#pragma unroll
      for (int j = 0; j < 4; ++j) {
        int row = j * 16 + l16;  // d
        int ca = quad ^ (row & 7);
        int cb = (4 + quad) ^ (row & 7);
        short8 v0 = *(const short8*)(Vb + row * 64 + ca * 8);
        short8 v1 = *(const short8*)(Vb + row * 64 + cb * 8);
        o[mi][j] = mfma16(ap0, v0, o[mi][j]);
        o[mi][j] = mfma16(ap1, v1, o[mi][j]);
      }
    }
  }
#undef STAGE

  // epilogue: full softmax denominator = sum of lp across the 4 quads
  // (lane (quad,l16) holds the partial for q=l16 over keys quad*8+e, +32).
#pragma unroll
  for (int mi = 0; mi < 2; ++mi) {
    lp[mi] += __shfl_xor(lp[mi], 16);
    lp[mi] += __shfl_xor(lp[mi], 32);
  }
  const int b_ = bh >> 4, h = bh & 15;
#pragma unroll
  for (int mi = 0; mi < 2; ++mi) {
    float dn[4];
#pragma unroll
    for (int r = 0; r < 4; ++r)
      dn[r] = __shfl(lp[mi], (lane & 48) + quad * 4 + r);  // denom for q-row quad*4+r
#pragma unroll
    for (int j = 0; j < 4; ++j)
#pragma unroll
      for (int r = 0; r < 4; ++r) {
        int t = qbase + mi * 64 + w * 16 + quad * 4 + r;
        int d = j * 16 + l16;
        ob[((size_t)(b_ * TSEQ + t)) * 1024 + h * 64 + d] =
            f2b(o[mi][j][r] / dn[r]);
      }
  }
}

// ------------------------------------------------------- out GEMM (fp32 out)
__global__ __launch_bounds__(256) void gemm_out_kernel(
    const u16* __restrict__ attn, const u16* __restrict__ Wt,
    const float* __restrict__ bias, float* __restrict__ out) {
  __shared__ __align__(16) u16 Asm[2 * 4096];
  __shared__ __align__(16) u16 Bsm[2 * 4096];
  f32x4 acc[4][4];
  const int m0 = blockIdx.y * 128;
  const int n0 = blockIdx.x * 128;
  gemm128_core(attn, Wt, m0, n0, Asm, Bsm, acc);

  const int tid = threadIdx.x;
  const int w = tid >> 6, lane = tid & 63, quad = lane >> 4, l16 = lane & 15;
  const int wm = (w >> 1) * 64, wn = (w & 1) * 64;
#pragma unroll
  for (int j = 0; j < 4; ++j) {
    int col = n0 + wn + j * 16 + l16;
    float bv = bias[col];
#pragma unroll
    for (int i = 0; i < 4; ++i)
#pragma unroll
      for (int r = 0; r < 4; ++r) {
        int m = m0 + wm + i * 16 + quad * 4 + r;
        out[(size_t)m * 1024 + col] = acc[i][j][r] + bv;
      }
  }
}

// ---------------------------------------------------------------- launcher
extern "C" void kernel_launch(void* const* d_in, const int* in_sizes, int n_in,
                              void* d_out, int out_size, void* d_ws, size_t ws_size,
                              hipStream_t stream) {
  const float* x    = (const float*)d_in[0];   // [8192][1024] fp32
  const float* Wqkv = (const float*)d_in[1];   // [1024][3072] fp32
  const float* bqkv = (const float*)d_in[2];   // [3072] fp32
  const float* Wout = (const float*)d_in[3];   // [1024][1024] fp32
  const float* bout = (const float*)d_in[4];   // [1024] fp32
  float* out = (float*)d_out;                  // [8192][1024] fp32

  u16* ws = (u16*)d_ws;
  u16* xb     = ws;                                  // 8M   bf16 x
  u16* wqkv_t = xb + (size_t)MROWS * 1024;           // 3M   [3072][1024]
  u16* wout_t = wqkv_t + (size_t)N3 * 1024;          // 1M   [1024][1024]
  u16* qbuf   = wout_t + (size_t)1024 * 1024;        // 8M   [bh][t][d]
  u16* kbuf   = qbuf + (size_t)MROWS * 1024;         // 8M   [bh][t][d]
  u16* vtbuf  = kbuf + (size_t)MROWS * 1024;         // 8M   [bh][d][t]
  u16* obuf   = vtbuf + (size_t)MROWS * 1024;        // 8M   [b][t][c]
  (void)ws_size; (void)n_in; (void)in_sizes; (void)out_size;

  int n4 = MROWS * 1024 / 4;
  cvt_f32_bf16<<<(n4 + 255) / 256, 256, 0, stream>>>(x, xb, n4);
  transpose_cvt<<<dim3(N3 / 32, 1024 / 32), dim3(32, 8), 0, stream>>>(Wqkv, wqkv_t, 1024, N3);
  transpose_cvt<<<dim3(1024 / 32, 1024 / 32), dim3(32, 8), 0, stream>>>(Wout, wout_t, 1024, 1024);
  gemm_qkv_kernel<<<dim3(N3 / 128, MROWS / 128), 256, 0, stream>>>(xb, wqkv_t, bqkv, qbuf, kbuf, vtbuf);
  attn_kernel<<<dim3(TSEQ / 128, BATCH * N_HEADS), 256, 0, stream>>>(qbuf, kbuf, vtbuf, obuf);
  gemm_out_kernel<<<dim3(1024 / 128, MROWS / 128), 256, 0, stream>>>(obuf, wout_t, bout, out);
}

// Round 5
// 293.566 us; speedup vs baseline: 1.0756x; 1.0044x over previous
//
#include <hip/hip_runtime.h>
#include <hip/hip_bf16.h>

// CausalSelfAttention on gfx950 — round 11.
// r10 post-mortem: clean per-dispatch A/B says the explicit pipelined core
// REGRESSED gemm_qkv (r8 sync-core 96us/MfmaUtil 22% -> r10 pipelined
// 120us/17.8%) — matches m131-m141 (source pipelining of m97 structure is
// neutral/negative; implicit wave overlap already covers it) + m190
// (setprio hurts lockstep GEMM). r9's "pipelined helped gemm_out by 38us"
// was a contaminated cross-round aggregate, not a counter.
// r11: (1) gemm_qkv reverted to the exact r8 sync core (single-buffer,
// __syncthreads, 16KiB LDS, no setprio); (2) gemm_out keeps the pipelined
// core (r10 best-total config, one variable at a time); (3) cvt + both
// weight transposes fused into ONE prep kernel (block-uniform branch,
// 256 thr everywhere) to kill two inter-launch gaps. attn unchanged.

typedef unsigned short u16;
typedef __attribute__((ext_vector_type(8))) short short8;
typedef __attribute__((ext_vector_type(4))) float f32x4;

#define N_HEADS 16
#define HEAD_DIM 64
#define TSEQ 2048
#define BATCH 4
#define MROWS (BATCH * TSEQ)   // 8192
#define N3 3072                // 3*D_MODEL

__device__ __forceinline__ void cp16(const u16* g, u16* l) {
  __builtin_amdgcn_global_load_lds((const __attribute__((address_space(1))) void*)g,
                                   (__attribute__((address_space(3))) void*)l, 16, 0, 0);
}

__device__ __forceinline__ f32x4 mfma16(short8 a, short8 b, f32x4 c) {
  return __builtin_amdgcn_mfma_f32_16x16x32_bf16(a, b, c, 0, 0, 0);
}

__device__ __forceinline__ u16 f2b(float f) {
  __hip_bfloat16 h = __float2bfloat16(f);
  return *reinterpret_cast<u16*>(&h);
}

// ---------------------------------------------------- fused prep kernel
// Grid partition (all parts use 256 flat threads, block-uniform branch):
//   [0, 8192)            : fp32 -> bf16 cvt of x (float4 per thread)
//   [8192, 8192+3072)    : transpose_cvt Wqkv  (Cn=3072, 96 c-tiles x 32 r-tiles)
//   [11264, 11264+1024)  : transpose_cvt Wout  (Cn=1024, 32 c-tiles x 32 r-tiles)
#define PREP_CVT_BLOCKS 8192
#define PREP_WQKV_BLOCKS (96 * 32)
#define PREP_WOUT_BLOCKS (32 * 32)
#define PREP_TOTAL (PREP_CVT_BLOCKS + PREP_WQKV_BLOCKS + PREP_WOUT_BLOCKS)

__device__ __forceinline__ void transpose_tile(const float* __restrict__ src,
                                               u16* __restrict__ dst,
                                               int R, int Cn, int c0, int r0,
                                               float (*tile)[33]) {
  const int tx = threadIdx.x & 31, ty = threadIdx.x >> 5;
  for (int i = ty; i < 32; i += 8)
    tile[i][tx] = src[(size_t)(r0 + i) * Cn + c0 + tx];
  __syncthreads();
  for (int i = ty; i < 32; i += 8)
    dst[(size_t)(c0 + i) * R + r0 + tx] = f2b(tile[tx][i]);
}

__global__ __launch_bounds__(256) void prep_kernel(
    const float* __restrict__ x, u16* __restrict__ xb,
    const float* __restrict__ Wqkv, u16* __restrict__ wqkv_t,
    const float* __restrict__ Wout, u16* __restrict__ wout_t) {
  __shared__ float tile[32][33];
  const int bx = blockIdx.x;
  if (bx < PREP_CVT_BLOCKS) {
    int i = bx * 256 + threadIdx.x;            // n4 = 8192*256 exactly
    float4 v = *(const float4*)(x + (size_t)i * 4);
    u16* d = xb + (size_t)i * 4;
    d[0] = f2b(v.x); d[1] = f2b(v.y); d[2] = f2b(v.z); d[3] = f2b(v.w);
  } else if (bx < PREP_CVT_BLOCKS + PREP_WQKV_BLOCKS) {
    int b2 = bx - PREP_CVT_BLOCKS;
    int c0 = (b2 % 96) * 32, r0 = (b2 / 96) * 32;
    transpose_tile(Wqkv, wqkv_t, 1024, N3, c0, r0, tile);
  } else {
    int b3 = bx - PREP_CVT_BLOCKS - PREP_WQKV_BLOCKS;
    int c0 = (b3 % 32) * 32, r0 = (b3 / 32) * 32;
    transpose_tile(Wout, wout_t, 1024, 1024, c0, r0, tile);
  }
}

// ------------------------------------------ 128^2 GEMM core, SYNC variant
// r8-measured 96us / MfmaUtil 22% on gemm_qkv. Single 16KiB LDS buffer,
// __syncthreads-drained staging (m97 structure). Do NOT pipeline: r10 A/B
// showed explicit dbuf+vmcnt+setprio costs 25% here.
__device__ __forceinline__ void gemm128_sync(const u16* __restrict__ A,
                                             const u16* __restrict__ Bt,
                                             int m0, int n0,
                                             u16* Asm, u16* Bsm,
                                             f32x4 acc[4][4]) {
  const int tid = threadIdx.x;
  const int w = tid >> 6;
  const int lane = tid & 63;
  const int quad = lane >> 4;
  const int l16 = lane & 15;
  const int wm = (w >> 1) * 64;
  const int wn = (w & 1) * 64;

#pragma unroll
  for (int i = 0; i < 4; ++i)
#pragma unroll
    for (int j = 0; j < 4; ++j) acc[i][j] = (f32x4){0.f, 0.f, 0.f, 0.f};

  for (int k0 = 0; k0 < 1024; k0 += 32) {
    __syncthreads();
#pragma unroll
    for (int p = 0; p < 2; ++p) {
      int s = p * 256 + tid;
      int row = s >> 2;
      int c4 = (s & 3) ^ ((row >> 1) & 3);
      cp16(A + (size_t)(m0 + row) * 1024 + k0 + c4 * 8,
           Asm + (size_t)(p * 256 + w * 64) * 8);
      cp16(Bt + (size_t)(n0 + row) * 1024 + k0 + c4 * 8,
           Bsm + (size_t)(p * 256 + w * 64) * 8);
    }
    __syncthreads();

    short8 a[4], b[4];
#pragma unroll
    for (int i = 0; i < 4; ++i) {
      int row = wm + i * 16 + l16;
      int c4 = quad ^ ((row >> 1) & 3);
      a[i] = *(const short8*)(Asm + row * 32 + c4 * 8);
    }
#pragma unroll
    for (int j = 0; j < 4; ++j) {
      int row = wn + j * 16 + l16;
      int c4 = quad ^ ((row >> 1) & 3);
      b[j] = *(const short8*)(Bsm + row * 32 + c4 * 8);
    }
#pragma unroll
    for (int i = 0; i < 4; ++i)
#pragma unroll
      for (int j = 0; j < 4; ++j)
        acc[i][j] = mfma16(a[i], b[j], acc[i][j]);
  }
}

// -------------------------------------------- 128^2 GEMM core, pipelined
// Double-buffered LDS, stage kt+2 after read-barrier, vmcnt(4) mid-loop.
// Kept for gemm_out only (r10 best-total config).
__device__ __forceinline__ void gemm128_pipe(const u16* __restrict__ A,
                                             const u16* __restrict__ Bt,
                                             int m0, int n0,
                                             u16* Asm, u16* Bsm,
                                             f32x4 acc[4][4]) {
  const int tid = threadIdx.x;
  const int w = tid >> 6;
  const int lane = tid & 63;
  const int quad = lane >> 4;
  const int l16 = lane & 15;
  const int wm = (w >> 1) * 64;
  const int wn = (w & 1) * 64;

#pragma unroll
  for (int i = 0; i < 4; ++i)
#pragma unroll
    for (int j = 0; j < 4; ++j) acc[i][j] = (f32x4){0.f, 0.f, 0.f, 0.f};

#define STG128(k0_, b_)                                                     \
  do {                                                                      \
    _Pragma("unroll")                                                       \
    for (int p = 0; p < 2; ++p) {                                           \
      int s = p * 256 + tid;                                                \
      int row = s >> 2;                                                     \
      int c4 = (s & 3) ^ ((row >> 1) & 3);                                  \
      cp16(A + (size_t)(m0 + row) * 1024 + (k0_) + c4 * 8,                  \
           Asm + (size_t)(b_) * 4096 + (p * 256 + w * 64) * 8);             \
      cp16(Bt + (size_t)(n0 + row) * 1024 + (k0_) + c4 * 8,                 \
           Bsm + (size_t)(b_) * 4096 + (p * 256 + w * 64) * 8);             \
    }                                                                       \
  } while (0)

  STG128(0, 0);
  STG128(32, 1);
  asm volatile("s_waitcnt vmcnt(4)" ::: "memory");  // tile 0 landed
  asm volatile("s_barrier" ::: "memory");

  for (int kt = 0; kt < 32; ++kt) {
    const u16* Ab = Asm + (kt & 1) * 4096;
    const u16* Bb = Bsm + (kt & 1) * 4096;
    short8 a[4], b[4];
#pragma unroll
    for (int i = 0; i < 4; ++i) {
      int row = wm + i * 16 + l16;
      int c4 = quad ^ ((row >> 1) & 3);
      a[i] = *(const short8*)(Ab + row * 32 + c4 * 8);
    }
#pragma unroll
    for (int j = 0; j < 4; ++j) {
      int row = wn + j * 16 + l16;
      int c4 = quad ^ ((row >> 1) & 3);
      b[j] = *(const short8*)(Bb + row * 32 + c4 * 8);
    }
#pragma unroll
    for (int i = 0; i < 4; ++i)
#pragma unroll
      for (int j = 0; j < 4; ++j)
        acc[i][j] = mfma16(a[i], b[j], acc[i][j]);

    asm volatile("s_barrier" ::: "memory");  // all waves done reading buf
    if (kt + 2 < 32) {
      STG128((kt + 2) * 32, kt & 1);         // into freed buf; stays in flight
      asm volatile("s_waitcnt vmcnt(4)" ::: "memory");  // tile kt+1 landed
    } else if (kt + 1 < 32) {
      asm volatile("s_waitcnt vmcnt(0)" ::: "memory");  // last tile: drain
    }
    asm volatile("s_barrier" ::: "memory");  // buf(kt+1) ready for all waves
  }
#undef STG128
}

// ---------------------------------------------------------------- QKV GEMM
__global__ __launch_bounds__(256) void gemm_qkv_kernel(
    const u16* __restrict__ x, const u16* __restrict__ Wt,
    const float* __restrict__ bias,
    u16* __restrict__ qb, u16* __restrict__ kb, u16* __restrict__ vtb) {
  __shared__ __align__(16) u16 Asm[128 * 32];
  __shared__ __align__(16) u16 Bsm[128 * 32];
  f32x4 acc[4][4];
  const int m0 = blockIdx.y * 128;
  const int n0 = blockIdx.x * 128;
  gemm128_sync(x, Wt, m0, n0, Asm, Bsm, acc);

  const int tid = threadIdx.x;
  const int w = tid >> 6, lane = tid & 63, quad = lane >> 4, l16 = lane & 15;
  const int wm = (w >> 1) * 64, wn = (w & 1) * 64;
#pragma unroll
  for (int j = 0; j < 4; ++j) {
    int col = n0 + wn + j * 16 + l16;
    float bv = bias[col];
    int which = col >> 10;     // 0=q 1=k 2=v
    int rem = col & 1023;
    int h = rem >> 6, d = rem & 63;
#pragma unroll
    for (int i = 0; i < 4; ++i) {
#pragma unroll
      for (int r = 0; r < 4; ++r) {
        int m = m0 + wm + i * 16 + quad * 4 + r;
        int b_ = m >> 11, t = m & 2047;
        int bh = b_ * N_HEADS + h;
        u16 o = f2b(acc[i][j][r] + bv);
        if (which == 0)
          qb[((size_t)(bh * TSEQ + t) << 6) + d] = o;
        else if (which == 1)
          kb[((size_t)(bh * TSEQ + t) << 6) + d] = o;
        else
          vtb[((size_t)((bh << 6) + d)) * TSEQ + t] = o;
      }
    }
  }
}

// ---------------------------------------------------------------- attention
// One block per (128-row q-tile, bh). 4 waves; wave w, m-frag mi covers q rows
// qt*128 + mi*64 + w*16 .. +15 (indexed by l16). K-tile = 64 keys, LDS
// double-buffer, raw barriers + fine-grained vmcnt (never 0 mid-loop).
// Swapped QK^T: s = mfma(Kfrag, Qfrag) -> lane (quad,l16) holds
// S[q=l16][key kappa(j*16+quad*4+r)] where the K staging placed key
// kappa(rho) = {rho5, rho3, rho2, rho4, rho1, rho0} at LDS row rho, i.e.
// lane quad holds exactly keys {quad*8+e} u {32+quad*8+e} — the PV A-operand
// k-slots. P never leaves the lane; no Psm, no lgkm drain.
__global__ __launch_bounds__(256, 5) void attn_kernel(const u16* __restrict__ qb,
                                                      const u16* __restrict__ kb,
                                                      const u16* __restrict__ vtb,
                                                      u16* __restrict__ ob) {
  const int qt = (TSEQ / 128 - 1) - blockIdx.x;  // 15..0 — heavy blocks first
  const int bh = blockIdx.y;                     // 0..63
  __shared__ __align__(16) u16 Ksm[2][4096];     // [buf][rho 64][d 64] swizzled
  __shared__ __align__(16) u16 Vsm[2][4096];     // [buf][d 64][t_k 64] swizzled
  const int tid = threadIdx.x;
  const int w = tid >> 6, lane = tid & 63, quad = lane >> 4, l16 = lane & 15;
  const int qbase = qt * 128;

  // Q fragments (B-operand layout == A-layout for 16x16x32), in registers
  short8 qf[2][2];
#pragma unroll
  for (int mi = 0; mi < 2; ++mi) {
    const u16* qr = qb + ((size_t)(bh * TSEQ + qbase + mi * 64 + w * 16 + l16)) * 64;
    qf[mi][0] = *(const short8*)(qr + quad * 8);
    qf[mi][1] = *(const short8*)(qr + 32 + quad * 8);
  }

  f32x4 o[2][4];
  float lp[2] = {0.f, 0.f};
#pragma unroll
  for (int mi = 0; mi < 2; ++mi)
#pragma unroll
    for (int j = 0; j < 4; ++j) o[mi][j] = (f32x4){0.f, 0.f, 0.f, 0.f};
  const float cexp = 0.18033688011112042f;  // (1/sqrt(64)) * log2(e)
  const float M = 10.0f;                    // static softmax shift

  const u16* kb_bh = kb + (size_t)bh * TSEQ * 64;
  const u16* vt_bh = vtb + (size_t)bh * 64 * TSEQ;
  const int nk = 2 * qt + 2;

  // stage k-tile kt into buffer b: 4 DMA issues per thread (vmcnt +=4).
  // K rows bit-permuted: LDS row rho <- key kappa(rho); V rows natural (d).
#define STAGE(kt_, b_)                                                        \
  do {                                                                        \
    const u16* kbase_ = kb_bh + (size_t)((kt_) * 64) * 64;                    \
    const u16* vbase_ = vt_bh + (kt_) * 64;                                   \
    _Pragma("unroll")                                                         \
    for (int p = 0; p < 2; ++p) {                                             \
      int s_ = p * 256 + tid;                                                 \
      int row_ = s_ >> 3;                                                     \
      int c8_ = (s_ & 7) ^ (row_ & 7);                                        \
      int krow_ = (row_ & 0x23) | ((row_ & 0x0C) << 1) | ((row_ & 0x10) >> 2);\
      cp16(kbase_ + krow_ * 64 + c8_ * 8, &Ksm[b_][(p * 256 + w * 64) * 8]);  \
      cp16(vbase_ + (size_t)row_ * TSEQ + c8_ * 8,                            \
           &Vsm[b_][(p * 256 + w * 64) * 8]);                                 \
    }                                                                         \
  } while (0)

  STAGE(0, 0);

  for (int kt = 0; kt < nk; ++kt) {
    // barrier 1: all waves finished READING buf((kt+1)&1) in iter kt-1
    asm volatile("s_barrier" ::: "memory");
    if (kt + 1 < nk) {
      STAGE(kt + 1, (kt + 1) & 1);               // DMA for kt+1 (stays in flight)
      asm volatile("s_waitcnt vmcnt(4)" ::: "memory");  // tile kt landed
    } else {
      asm volatile("s_waitcnt vmcnt(0)" ::: "memory");  // last tile: drain
    }
    // barrier 2: all waves' tile-kt DMA landed
    asm volatile("s_barrier" ::: "memory");

    const u16* Kb = Ksm[kt & 1];
    const u16* Vb = Vsm[kt & 1];

#pragma unroll
    for (int mi = 0; mi < 2; ++mi) {
      const int qmin = qbase + mi * 64 + w * 16;
      if (kt * 64 > qmin + 15) continue;   // whole fragment masked
      const int qlane = qmin + l16;

      // S^T = K Q^T : lane (quad,l16) gets S[q=l16][kappa(j*16+quad*4+r)]
      f32x4 s[4];
#pragma unroll
      for (int j = 0; j < 4; ++j) {
        int row = j * 16 + l16;
        int ca = quad ^ (row & 7);
        int cb = (4 + quad) ^ (row & 7);
        short8 k0 = *(const short8*)(Kb + row * 64 + ca * 8);
        short8 k1 = *(const short8*)(Kb + row * 64 + cb * 8);
        f32x4 z = (f32x4){0.f, 0.f, 0.f, 0.f};
        z = mfma16(k0, qf[mi][0], z);
        z = mfma16(k1, qf[mi][1], z);
        s[j] = z;
      }
      if (kt * 64 + 63 > qmin) {  // diagonal overlap: elementwise causal mask
#pragma unroll
        for (int j = 0; j < 4; ++j) {
#pragma unroll
          for (int r = 0; r < 4; ++r) {
            int kabs = kt * 64 + ((j >> 1) << 5) + (quad << 3) + ((j & 1) << 2) + r;
            if (kabs > qlane) s[j][r] = -1e30f;
          }
        }
      }
      // static-max softmax: p = exp2(s*cexp - M); pack straight into the
      // PV A-operand fragments (keys already lane-local in k-slot order).
      short8 ap0, ap1;
#pragma unroll
      for (int j = 0; j < 4; ++j) {
#pragma unroll
        for (int r = 0; r < 4; ++r) {
          float p_ = __builtin_amdgcn_exp2f(__builtin_fmaf(s[j][r], cexp, -M));
          lp[mi] += p_;
          u16 pb = f2b(p_);
          if (j < 2) ap0[j * 4 + r] = (short)pb;
          else       ap1[(j - 2) * 4 + r] = (short)pb;
        }
      }
      // O += P V : A = P (rows q=l16, k = quad*8+e), B = V^T (cols d=l16)
#pragma unroll
      for (int j = 0; j < 4; ++j) {
        int row = j * 16 + l16;  // d
        int ca = quad ^ (row & 7);
        int cb = (4 + quad) ^ (row & 7);
        short8 v0 = *(const short8*)(Vb + row * 64 + ca * 8);
        short8 v1 = *(const short8*)(Vb + row * 64 + cb * 8);
        o[mi][j] = mfma16(ap0, v0, o[mi][j]);
        o[mi][j] = mfma16(ap1, v1, o[mi][j]);
      }
    }
  }
#undef STAGE

  // epilogue: full softmax denominator = sum of lp across the 4 quads
  // (lane (quad,l16) holds the partial for q=l16 over keys quad*8+e, +32).
#pragma unroll
  for (int mi = 0; mi < 2; ++mi) {
    lp[mi] += __shfl_xor(lp[mi], 16);
    lp[mi] += __shfl_xor(lp[mi], 32);
  }
  const int b_ = bh >> 4, h = bh & 15;
#pragma unroll
  for (int mi = 0; mi < 2; ++mi) {
    float dn[4];
#pragma unroll
    for (int r = 0; r < 4; ++r)
      dn[r] = __shfl(lp[mi], (lane & 48) + quad * 4 + r);  // denom for q-row quad*4+r
#pragma unroll
    for (int j = 0; j < 4; ++j)
#pragma unroll
      for (int r = 0; r < 4; ++r) {
        int t = qbase + mi * 64 + w * 16 + quad * 4 + r;
        int d = j * 16 + l16;
        ob[((size_t)(b_ * TSEQ + t)) * 1024 + h * 64 + d] =
            f2b(o[mi][j][r] / dn[r]);
      }
  }
}

// ------------------------------------------------------- out GEMM (fp32 out)
__global__ __launch_bounds__(256) void gemm_out_kernel(
    const u16* __restrict__ attn, const u16* __restrict__ Wt,
    const float* __restrict__ bias, float* __restrict__ out) {
  __shared__ __align__(16) u16 Asm[2 * 4096];
  __shared__ __align__(16) u16 Bsm[2 * 4096];
  f32x4 acc[4][4];
  const int m0 = blockIdx.y * 128;
  const int n0 = blockIdx.x * 128;
  gemm128_pipe(attn, Wt, m0, n0, Asm, Bsm, acc);

  const int tid = threadIdx.x;
  const int w = tid >> 6, lane = tid & 63, quad = lane >> 4, l16 = lane & 15;
  const int wm = (w >> 1) * 64, wn = (w & 1) * 64;
#pragma unroll
  for (int j = 0; j < 4; ++j) {
    int col = n0 + wn + j * 16 + l16;
    float bv = bias[col];
#pragma unroll
    for (int i = 0; i < 4; ++i)
#pragma unroll
      for (int r = 0; r < 4; ++r) {
        int m = m0 + wm + i * 16 + quad * 4 + r;
        out[(size_t)m * 1024 + col] = acc[i][j][r] + bv;
      }
  }
}

// ---------------------------------------------------------------- launcher
extern "C" void kernel_launch(void* const* d_in, const int* in_sizes, int n_in,
                              void* d_out, int out_size, void* d_ws, size_t ws_size,
                              hipStream_t stream) {
  const float* x    = (const float*)d_in[0];   // [8192][1024] fp32
  const float* Wqkv = (const float*)d_in[1];   // [1024][3072] fp32
  const float* bqkv = (const float*)d_in[2];   // [3072] fp32
  const float* Wout = (const float*)d_in[3];   // [1024][1024] fp32
  const float* bout = (const float*)d_in[4];   // [1024] fp32
  float* out = (float*)d_out;                  // [8192][1024] fp32

  u16* ws = (u16*)d_ws;
  u16* xb     = ws;                                  // 8M   bf16 x
  u16* wqkv_t = xb + (size_t)MROWS * 1024;           // 3M   [3072][1024]
  u16* wout_t = wqkv_t + (size_t)N3 * 1024;          // 1M   [1024][1024]
  u16* qbuf   = wout_t + (size_t)1024 * 1024;        // 8M   [bh][t][d]
  u16* kbuf   = qbuf + (size_t)MROWS * 1024;         // 8M   [bh][t][d]
  u16* vtbuf  = kbuf + (size_t)MROWS * 1024;         // 8M   [bh][d][t]
  u16* obuf   = vtbuf + (size_t)MROWS * 1024;        // 8M   [b][t][c]
  (void)ws_size; (void)n_in; (void)in_sizes; (void)out_size;

  prep_kernel<<<PREP_TOTAL, 256, 0, stream>>>(x, xb, Wqkv, wqkv_t, Wout, wout_t);
  gemm_qkv_kernel<<<dim3(N3 / 128, MROWS / 128), 256, 0, stream>>>(xb, wqkv_t, bqkv, qbuf, kbuf, vtbuf);
  attn_kernel<<<dim3(TSEQ / 128, BATCH * N_HEADS), 256, 0, stream>>>(qbuf, kbuf, vtbuf, obuf);
  gemm_out_kernel<<<dim3(1024 / 128, MROWS / 128), 256, 0, stream>>>(obuf, wout_t, bout, out);
}